// Round 7
// baseline (14316.307 us; speedup 1.0000x reference)
//
#include <hip/hip_runtime.h>

#define NT 64
#define NB 262144

struct P {
  const float* node_feat; const float* edge_feat; const int* ei;
  const float* W_ne; const float* b_ne; const float* g_ne; const float* be_ne;
  const float* W_ee; const float* b_ee;
  const float* msg_W1; const float* msg_b1; const float* msg_W2; const float* msg_b2;
  const float* upd_W1; const float* upd_b1; const float* upd_g1; const float* upd_be1;
  const float* upd_W2; const float* upd_b2; const float* upd_g2; const float* upd_be2;
  const float* Wp; const float* bp; const float* gp; const float* bep;
  const float* mW1; const float* mb1; const float* mg1; const float* mbe1;
  const float* mW2; const float* mb2; const float* mg2; const float* mbe2;
  const float* mW3; const float* mb3; const float* mg3; const float* mbe3;
  const float* mW4; const float* mb4;
  float* out;
};

// 1/sqrt(1+1e-5)
#define INVC 0.9999950000374997f

__device__ __forceinline__ float sigm(float x) {
  return __builtin_amdgcn_rcpf(1.0f + __expf(-x));
}

// copy x[n] -> o with n a wave-uniform runtime index; static register indices only
__device__ __forceinline__ void sel5(const float (&x)[5][16], int n, float (&o)[16]) {
#pragma unroll
  for (int j = 0; j < 16; j++) {
    float v = x[0][j];
    v = (n == 1) ? x[1][j] : v;
    v = (n == 2) ? x[2][j] : v;
    v = (n == 3) ? x[3][j] : v;
    v = (n == 4) ? x[4][j] : v;
    o[j] = v;
  }
}

// LDS: 80 rows * 64 cols * 4B = 20 KiB/block.
//  - during GNN layers: agg[n][d] at row n*16+d (column t = this thread's graph)
//  - during MLP head:   h[64] at rows 0..63
// Column-per-thread => bank = t%32 (2 lanes/bank, free), zero barriers.
// __launch_bounds__(64, 1): occupancy-1 floor — the ONLY config (R3) that has
// not spilled. Do not raise the floor: (64,2)/(256,2) both triggered 128-VGPR
// caps and multi-GB scratch traffic (R5/R6).
__global__ __launch_bounds__(NT, 1) void gnn_kernel(P p) {
  const int t = threadIdx.x;
  const int g = blockIdx.x * NT + t;

  __shared__ float as_[80][NT];

  // ---------------- edge indices -> SGPRs (statically indexed everywhere) ----------------
  int se_[8], de_[8];
#pragma unroll
  for (int e = 0; e < 8; e++) {
    se_[e] = __builtin_amdgcn_readfirstlane(p.ei[e]);
    de_[e] = __builtin_amdgcn_readfirstlane(p.ei[8 + e]);
  }
  float dr_[5];
#pragma unroll
  for (int n = 0; n < 5; n++) {
    int c = 0;
#pragma unroll
    for (int e = 0; e < 8; e++) c += (de_[e] == n) ? 1 : 0;
    dr_[n] = 1.0f / (float)(c > 1 ? c : 1);
  }

  // ---------------- node encoder: x[5][16] in REGISTERS ----------------
  float x[5][16];
#pragma unroll
  for (int n = 0; n < 5; n++) {
    float nfv[7];
#pragma unroll
    for (int k = 0; k < 7; k++) nfv[k] = p.node_feat[(size_t)g * 35 + n * 7 + k];
    const float gn = p.g_ne[n] * INVC;
    const float bn_ = p.be_ne[n];
#pragma unroll
    for (int d = 0; d < 16; d++) {
      float a = p.b_ne[d];
#pragma unroll
      for (int k = 0; k < 7; k++) a = fmaf(nfv[k], p.W_ne[k * 16 + d], a);
      x[n][d] = fmaf(gn, a, bn_);
    }
  }

  // ---------------- raw edge features in registers ----------------
  float ef[16];
  {
    const float4* efv = reinterpret_cast<const float4*>(p.edge_feat + (size_t)g * 16);
#pragma unroll
    for (int q = 0; q < 4; q++) {
      float4 v = efv[q];
      ef[q * 4 + 0] = v.x; ef[q * 4 + 1] = v.y;
      ef[q * 4 + 2] = v.z; ef[q * 4 + 3] = v.w;
    }
  }

  // ---------------- L message-passing layers ----------------
#pragma unroll 1
  for (int l = 0; l < 4; l++) {
    const float* mW1 = p.msg_W1 + l * 576;
    const float* mb1 = p.msg_b1 + l * 16;
    const float* mW2 = p.msg_W2 + l * 256;
    const float* mb2 = p.msg_b2 + l * 16;
    const float* uW1 = p.upd_W1 + l * 512;
    const float* ub1 = p.upd_b1 + l * 16;
    const float* ug1 = p.upd_g1 + l * 5;
    const float* ube1 = p.upd_be1 + l * 5;
    const float* uW2 = p.upd_W2 + l * 256;
    const float* ub2 = p.upd_b2 + l * 16;
    const float* ug2 = p.upd_g2 + l * 5;
    const float* ube2 = p.upd_be2 + l * 5;

    // zero agg rows (own column only)
#pragma unroll
    for (int r = 0; r < 80; r++) as_[r][t] = 0.f;

    // ---- phase A: per-edge messages; pure register/SMEM FMA stream, LDS only at tail ----
#pragma unroll
    for (int e = 0; e < 8; e++) {
      const int se = se_[e], de = de_[e];

      float m1[16];
#pragma unroll
      for (int d = 0; d < 16; d++) m1[d] = mb1[d];

      float hx[16];                 // single shared buffer for h_i then h_j
      sel5(x, de, hx);
#pragma unroll
      for (int k = 0; k < 16; k++)
#pragma unroll
        for (int d = 0; d < 16; d++) m1[d] = fmaf(hx[k], mW1[k * 16 + d], m1[d]);
      sel5(x, se, hx);
#pragma unroll
      for (int k = 0; k < 16; k++)
#pragma unroll
        for (int d = 0; d < 16; d++) m1[d] = fmaf(hx[k], mW1[(16 + k) * 16 + d], m1[d]);
      {
        const float e0 = ef[2 * e], e1 = ef[2 * e + 1];
#pragma unroll
        for (int j = 0; j < 4; j++) {
          float ea = fmaf(e0, p.W_ee[j], fmaf(e1, p.W_ee[4 + j], p.b_ee[j]));
#pragma unroll
          for (int d = 0; d < 16; d++) m1[d] = fmaf(ea, mW1[(32 + j) * 16 + d], m1[d]);
        }
      }
#pragma unroll
      for (int d = 0; d < 16; d++) m1[d] = sigm(m1[d]);

      // m2 -> accumulate into LDS agg row (runtime uniform row base, fine for LDS)
#pragma unroll
      for (int d = 0; d < 16; d++) {
        float a = mb2[d];
#pragma unroll
        for (int k = 0; k < 16; k++) a = fmaf(m1[k], mW2[k * 16 + d], a);
        as_[de * 16 + d][t] += sigm(a);
      }
    }

    // ---- phase B: per-node update, x[n] += u2 (n unrolled -> all x indices static) ----
#pragma unroll
    for (int n = 0; n < 5; n++) {
      float an[16];
#pragma unroll
      for (int k = 0; k < 16; k++) an[k] = as_[n * 16 + k][t] * dr_[n];

      float a1[16];
#pragma unroll
      for (int d = 0; d < 16; d++) a1[d] = ub1[d];
#pragma unroll
      for (int k = 0; k < 16; k++)
#pragma unroll
        for (int d = 0; d < 16; d++) a1[d] = fmaf(x[n][k], uW1[k * 16 + d], a1[d]);
#pragma unroll
      for (int k = 0; k < 16; k++)
#pragma unroll
        for (int d = 0; d < 16; d++) a1[d] = fmaf(an[k], uW1[(16 + k) * 16 + d], a1[d]);

      const float G1 = ug1[n] * INVC, B1 = ube1[n];
      // u1 overwrites a1 (saves 16 live regs)
#pragma unroll
      for (int d = 0; d < 16; d++) a1[d] = sigm(fmaf(G1, a1[d], B1));

      const float G2 = ug2[n] * INVC, B2 = ube2[n];
#pragma unroll
      for (int d = 0; d < 16; d++) {
        float a = ub2[d];
#pragma unroll
        for (int k = 0; k < 16; k++) a = fmaf(a1[k], uW2[k * 16 + d], a);
        x[n][d] += sigm(fmaf(G2, a, B2));
      }
    }
  }

  // ---------------- pooling: p1 = sigmoid(bnc(x.reshape(80) @ Wp + bp)) ----------------
  float p1[16];
  {
#pragma unroll
    for (int d = 0; d < 16; d++) p1[d] = p.bp[d];
#pragma unroll
    for (int n = 0; n < 5; n++)
#pragma unroll
      for (int k = 0; k < 16; k++) {
        const float xv = x[n][k];
#pragma unroll
        for (int d = 0; d < 16; d++)
          p1[d] = fmaf(xv, p.Wp[(n * 16 + k) * 16 + d], p1[d]);
      }
#pragma unroll
    for (int d = 0; d < 16; d++)
      p1[d] = sigm(fmaf(p.gp[d] * INVC, p1[d], p.bep[d]));
  }

  // ---------------- MLP head (x dead; registers free; h lives in LDS rows 0..63) ----------------
  // mlp1: p1(regs) -> rows 0..63
  {
    float acc[4][16];
#pragma unroll
    for (int c = 0; c < 4; c++)
#pragma unroll
      for (int d = 0; d < 16; d++) acc[c][d] = p.mb1[c * 16 + d];
#pragma unroll 2
    for (int k = 0; k < 16; k++) {
      const float hv = p1[k];
#pragma unroll
      for (int c = 0; c < 4; c++)
#pragma unroll
        for (int d = 0; d < 16; d++)
          acc[c][d] = fmaf(hv, p.mW1[k * 64 + c * 16 + d], acc[c][d]);
    }
#pragma unroll
    for (int c = 0; c < 4; c++)
#pragma unroll
      for (int d = 0; d < 16; d++)
        as_[c * 16 + d][t] = sigm(fmaf(p.mg1[c * 16 + d] * INVC, acc[c][d], p.mbe1[c * 16 + d]));
  }
  // mlp2: rows 0..63 -> rows 0..63 (single k-pass with 64 accumulators, then write)
  {
    float acc[4][16];
#pragma unroll
    for (int c = 0; c < 4; c++)
#pragma unroll
      for (int d = 0; d < 16; d++) acc[c][d] = p.mb2[c * 16 + d];
#pragma unroll 2
    for (int k = 0; k < 64; k++) {
      const float hv = as_[k][t];
#pragma unroll
      for (int c = 0; c < 4; c++)
#pragma unroll
        for (int d = 0; d < 16; d++)
          acc[c][d] = fmaf(hv, p.mW2[k * 64 + c * 16 + d], acc[c][d]);
    }
#pragma unroll
    for (int c = 0; c < 4; c++)
#pragma unroll
      for (int d = 0; d < 16; d++)
        as_[c * 16 + d][t] = sigm(fmaf(p.mg2[c * 16 + d] * INVC, acc[c][d], p.mbe2[c * 16 + d]));
  }
  // mlp3: rows 0..63 -> rows 0..63
  {
    float acc[4][16];
#pragma unroll
    for (int c = 0; c < 4; c++)
#pragma unroll
      for (int d = 0; d < 16; d++) acc[c][d] = p.mb3[c * 16 + d];
#pragma unroll 2
    for (int k = 0; k < 64; k++) {
      const float hv = as_[k][t];
#pragma unroll
      for (int c = 0; c < 4; c++)
#pragma unroll
        for (int d = 0; d < 16; d++)
          acc[c][d] = fmaf(hv, p.mW3[k * 64 + c * 16 + d], acc[c][d]);
    }
#pragma unroll
    for (int c = 0; c < 4; c++)
#pragma unroll
      for (int d = 0; d < 16; d++)
        as_[c * 16 + d][t] = sigm(fmaf(p.mg3[c * 16 + d] * INVC, acc[c][d], p.mbe3[c * 16 + d]));
  }
  // mlp4: rows 0..63 -> out (4 partial sums)
  {
    float a0 = p.mb4[0], a1 = 0.f, a2 = 0.f, a3 = 0.f;
#pragma unroll 2
    for (int k = 0; k < 16; k++) {
      a0 = fmaf(as_[k * 4 + 0][t], p.mW4[k * 4 + 0], a0);
      a1 = fmaf(as_[k * 4 + 1][t], p.mW4[k * 4 + 1], a1);
      a2 = fmaf(as_[k * 4 + 2][t], p.mW4[k * 4 + 2], a2);
      a3 = fmaf(as_[k * 4 + 3][t], p.mW4[k * 4 + 3], a3);
    }
    p.out[g] = (a0 + a1) + (a2 + a3);
  }
}

extern "C" void kernel_launch(void* const* d_in, const int* in_sizes, int n_in,
                              void* d_out, int out_size, void* d_ws, size_t ws_size,
                              hipStream_t stream) {
  P p;
  p.node_feat = (const float*)d_in[0];
  p.edge_feat = (const float*)d_in[1];
  p.ei        = (const int*)d_in[2];
  p.W_ne  = (const float*)d_in[3];  p.b_ne  = (const float*)d_in[4];
  p.g_ne  = (const float*)d_in[5];  p.be_ne = (const float*)d_in[6];
  p.W_ee  = (const float*)d_in[7];  p.b_ee  = (const float*)d_in[8];
  p.msg_W1 = (const float*)d_in[9];  p.msg_b1 = (const float*)d_in[10];
  p.msg_W2 = (const float*)d_in[11]; p.msg_b2 = (const float*)d_in[12];
  p.upd_W1 = (const float*)d_in[13]; p.upd_b1 = (const float*)d_in[14];
  p.upd_g1 = (const float*)d_in[15]; p.upd_be1 = (const float*)d_in[16];
  p.upd_W2 = (const float*)d_in[17]; p.upd_b2 = (const float*)d_in[18];
  p.upd_g2 = (const float*)d_in[19]; p.upd_be2 = (const float*)d_in[20];
  p.Wp  = (const float*)d_in[21]; p.bp  = (const float*)d_in[22];
  p.gp  = (const float*)d_in[23]; p.bep = (const float*)d_in[24];
  p.mW1 = (const float*)d_in[25]; p.mb1 = (const float*)d_in[26];
  p.mg1 = (const float*)d_in[27]; p.mbe1 = (const float*)d_in[28];
  p.mW2 = (const float*)d_in[29]; p.mb2 = (const float*)d_in[30];
  p.mg2 = (const float*)d_in[31]; p.mbe2 = (const float*)d_in[32];
  p.mW3 = (const float*)d_in[33]; p.mb3 = (const float*)d_in[34];
  p.mg3 = (const float*)d_in[35]; p.mbe3 = (const float*)d_in[36];
  p.mW4 = (const float*)d_in[37]; p.mb4 = (const float*)d_in[38];
  p.out = (float*)d_out;

  hipLaunchKernelGGL(gnn_kernel, dim3(NB / NT), dim3(NT), 0, stream, p);
}

// Round 8
// 2153.354 us; speedup vs baseline: 6.6484x; 6.6484x over previous
//
#include <hip/hip_runtime.h>

#define NT 64
#define NB 262144

struct P {
  const float* node_feat; const float* edge_feat; const int* ei;
  const float* W_ne; const float* b_ne; const float* g_ne; const float* be_ne;
  const float* W_ee; const float* b_ee;
  const float* msg_W1; const float* msg_b1; const float* msg_W2; const float* msg_b2;
  const float* upd_W1; const float* upd_b1; const float* upd_g1; const float* upd_be1;
  const float* upd_W2; const float* upd_b2; const float* upd_g2; const float* upd_be2;
  const float* Wp; const float* bp; const float* gp; const float* bep;
  const float* mW1; const float* mb1; const float* mg1; const float* mbe1;
  const float* mW2; const float* mb2; const float* mg2; const float* mbe2;
  const float* mW3; const float* mb3; const float* mg3; const float* mbe3;
  const float* mW4; const float* mb4;
  float* out;
};

// 1/sqrt(1+1e-5)
#define INVC 0.9999950000374997f

__device__ __forceinline__ float sigm(float x) {
  return __builtin_amdgcn_rcpf(1.0f + __expf(-x));
}

// a[0..15] += hv * w[0..15], w read as 4x float4 (ds_read_b128 broadcast when w is LDS)
__device__ __forceinline__ void fma16(float hv, const float* w, float (&a)[16]) {
  const float4* wr = (const float4*)w;
  float4 w0 = wr[0], w1 = wr[1], w2 = wr[2], w3 = wr[3];
  a[0]  = fmaf(hv, w0.x, a[0]);  a[1]  = fmaf(hv, w0.y, a[1]);
  a[2]  = fmaf(hv, w0.z, a[2]);  a[3]  = fmaf(hv, w0.w, a[3]);
  a[4]  = fmaf(hv, w1.x, a[4]);  a[5]  = fmaf(hv, w1.y, a[5]);
  a[6]  = fmaf(hv, w1.z, a[6]);  a[7]  = fmaf(hv, w1.w, a[7]);
  a[8]  = fmaf(hv, w2.x, a[8]);  a[9]  = fmaf(hv, w2.y, a[9]);
  a[10] = fmaf(hv, w2.z, a[10]); a[11] = fmaf(hv, w2.w, a[11]);
  a[12] = fmaf(hv, w3.x, a[12]); a[13] = fmaf(hv, w3.y, a[13]);
  a[14] = fmaf(hv, w3.z, a[14]); a[15] = fmaf(hv, w3.w, a[15]);
}

// LDS layout:
//  xs[176][64] column-per-thread (bank = t%32, 2 lanes/bank = free):
//   rows  0..79 : x[n][d] = row n*16+d
//   rows 80..95 : raw edge_feat; later the pooled vector p1
//   rows 96..175: agg[n][d] during GNN; later raw float region for mW2/mW3 (4096 f)
//  wl[1600]: per-layer weights staged from global (mW1|mW2|uW1|uW2), broadcast reads;
//            later Wp (1280), then mlp mW1 (1024) + mW4 (64).
// Block = 1 wave: no cross-wave hazards; __syncthreads() after staging is ~free.
// __launch_bounds__(64,1): the only non-spilling config (R3/R8); x MUST stay in LDS.
__global__ __launch_bounds__(NT, 1) void gnn_kernel(P p) {
  const int t = threadIdx.x;
  const int g = blockIdx.x * NT + t;

  __shared__ __align__(16) float xs[176][NT];
  __shared__ __align__(16) float wl[1600];

  // ---------------- node encoder: x = bn5(node_feat @ W_ne + b_ne) -> rows 0..79 ----------------
#pragma unroll
  for (int n = 0; n < 5; n++) {
    float nfv[7];
#pragma unroll
    for (int k = 0; k < 7; k++) nfv[k] = p.node_feat[(size_t)g * 35 + n * 7 + k];
    const float gn = p.g_ne[n] * INVC;
    const float bn_ = p.be_ne[n];
#pragma unroll
    for (int d = 0; d < 16; d++) {
      float a = p.b_ne[d];
#pragma unroll
      for (int k = 0; k < 7; k++) a = fmaf(nfv[k], p.W_ne[k * 16 + d], a);
      xs[n * 16 + d][t] = fmaf(gn, a, bn_);
    }
  }

  // ---------------- raw edge features -> rows 80..95 ----------------
  {
    const float4* efv = reinterpret_cast<const float4*>(p.edge_feat + (size_t)g * 16);
#pragma unroll
    for (int q = 0; q < 4; q++) {
      float4 v = efv[q];
      xs[80 + q * 4 + 0][t] = v.x;
      xs[80 + q * 4 + 1][t] = v.y;
      xs[80 + q * 4 + 2][t] = v.z;
      xs[80 + q * 4 + 3][t] = v.w;
    }
  }

  // ---------------- L message-passing layers ----------------
#pragma unroll 1
  for (int l = 0; l < 4; l++) {
    // ---- stage this layer's weights into wl (float4 cooperative copy) ----
    {
      float4* d4 = (float4*)wl;
      const float4* s1 = (const float4*)(p.msg_W1 + l * 576);  // 144 f4 @ 0
#pragma unroll 1
      for (int i = t; i < 144; i += NT) d4[i] = s1[i];
      const float4* s2 = (const float4*)(p.msg_W2 + l * 256);  // 64 f4 @ 144
      d4[144 + t] = s2[t];
      const float4* s3 = (const float4*)(p.upd_W1 + l * 512);  // 128 f4 @ 208
      d4[208 + t] = s3[t];
      d4[208 + NT + t] = s3[NT + t];
      const float4* s4 = (const float4*)(p.upd_W2 + l * 256);  // 64 f4 @ 336
      d4[336 + t] = s4[t];
    }
    __syncthreads();

    // zero agg rows
#pragma unroll
    for (int r = 0; r < 80; r++) xs[96 + r][t] = 0.f;

    // ---- phase A: per-edge messages; weights broadcast from LDS ----
#pragma unroll 1
    for (int e = 0; e < 8; e++) {
      const int se = __builtin_amdgcn_readfirstlane(p.ei[e]);
      const int de = __builtin_amdgcn_readfirstlane(p.ei[8 + e]);

      float m1[16];
#pragma unroll
      for (int d = 0; d < 16; d++) m1[d] = p.msg_b1[l * 16 + d];
#pragma unroll
      for (int k = 0; k < 16; k++) fma16(xs[de * 16 + k][t], &wl[k * 16], m1);
#pragma unroll
      for (int k = 0; k < 16; k++) fma16(xs[se * 16 + k][t], &wl[256 + k * 16], m1);
      {
        const float e0 = xs[80 + 2 * e][t], e1 = xs[81 + 2 * e][t];
#pragma unroll
        for (int j = 0; j < 4; j++) {
          float ea = fmaf(e0, p.W_ee[j], fmaf(e1, p.W_ee[4 + j], p.b_ee[j]));
          fma16(ea, &wl[512 + j * 16], m1);
        }
      }
#pragma unroll
      for (int d = 0; d < 16; d++) m1[d] = sigm(m1[d]);

      float a2[16];
#pragma unroll
      for (int d = 0; d < 16; d++) a2[d] = p.msg_b2[l * 16 + d];
#pragma unroll
      for (int k = 0; k < 16; k++) fma16(m1[k], &wl[576 + k * 16], a2);
#pragma unroll
      for (int d = 0; d < 16; d++) as_rmw: ;
#pragma unroll
      for (int d = 0; d < 16; d++) xs[96 + de * 16 + d][t] += sigm(a2[d]);
    }

    // ---- phase B: per-node update; weights broadcast from LDS ----
#pragma unroll 1
    for (int n = 0; n < 5; n++) {
      int c = 0;
#pragma unroll
      for (int e = 0; e < 8; e++)
        c += (__builtin_amdgcn_readfirstlane(p.ei[8 + e]) == n) ? 1 : 0;
      const float dr = 1.0f / (float)(c > 1 ? c : 1);

      float a1[16];
#pragma unroll
      for (int d = 0; d < 16; d++) a1[d] = p.upd_b1[l * 16 + d];
#pragma unroll
      for (int k = 0; k < 16; k++) fma16(xs[n * 16 + k][t], &wl[832 + k * 16], a1);
#pragma unroll
      for (int k = 0; k < 16; k++) fma16(xs[96 + n * 16 + k][t] * dr, &wl[1088 + k * 16], a1);

      const float G1 = p.upd_g1[l * 5 + n] * INVC, B1 = p.upd_be1[l * 5 + n];
#pragma unroll
      for (int d = 0; d < 16; d++) a1[d] = sigm(fmaf(G1, a1[d], B1));

      float a2[16];
#pragma unroll
      for (int d = 0; d < 16; d++) a2[d] = p.upd_b2[l * 16 + d];
#pragma unroll
      for (int k = 0; k < 16; k++) fma16(a1[k], &wl[1344 + k * 16], a2);

      const float G2 = p.upd_g2[l * 5 + n] * INVC, B2 = p.upd_be2[l * 5 + n];
#pragma unroll
      for (int d = 0; d < 16; d++) xs[n * 16 + d][t] += sigm(fmaf(G2, a2[d], B2));
    }
  }

  // ---------------- pooling: p1 = sigmoid(bnc(x.reshape(80) @ Wp + bp)) -> rows 80..95 ----------------
  {
    float4* d4 = (float4*)wl;
    const float4* s = (const float4*)p.Wp;  // 320 f4
#pragma unroll 1
    for (int i = t; i < 320; i += NT) d4[i] = s[i];
  }
  __syncthreads();
  {
    float a[16];
#pragma unroll
    for (int d = 0; d < 16; d++) a[d] = p.bp[d];
#pragma unroll 4
    for (int k = 0; k < 80; k++) fma16(xs[k][t], &wl[k * 16], a);
#pragma unroll
    for (int d = 0; d < 16; d++)
      xs[80 + d][t] = sigm(fmaf(p.gp[d] * INVC, a[d], p.bep[d]));
  }

  // ---------------- MLP head ----------------
  // stage mlp mW1 (256 f4 @ wl0) + mW4 (16 f4 @ wl[1024])
  {
    float4* d4 = (float4*)wl;
    const float4* s1 = (const float4*)p.mW1;
#pragma unroll 1
    for (int i = t; i < 256; i += NT) d4[i] = s1[i];
    if (t < 16) d4[256 + t] = ((const float4*)p.mW4)[t];
  }
  __syncthreads();
  // mlp1: rows 80..95 (16) -> rows 0..63
  {
    float acc[4][16];
#pragma unroll
    for (int c = 0; c < 4; c++)
#pragma unroll
      for (int d = 0; d < 16; d++) acc[c][d] = p.mb1[c * 16 + d];
#pragma unroll 4
    for (int k = 0; k < 16; k++) {
      const float hv = xs[80 + k][t];
#pragma unroll
      for (int c = 0; c < 4; c++) fma16(hv, &wl[k * 64 + c * 16], acc[c]);
    }
#pragma unroll
    for (int c = 0; c < 4; c++)
#pragma unroll
      for (int d = 0; d < 16; d++)
        xs[c * 16 + d][t] = sigm(fmaf(p.mg1[c * 16 + d] * INVC, acc[c][d], p.mbe1[c * 16 + d]));
  }
  // mlp2: stage mW2 (1024 f4) into rows 96..175, then rows 0..63 -> rows 0..63
  float* mlpw = &xs[96][0];
  {
    float4* d4 = (float4*)mlpw;
    const float4* s = (const float4*)p.mW2;
#pragma unroll 1
    for (int i = t; i < 1024; i += NT) d4[i] = s[i];
  }
  __syncthreads();
  {
    float acc[4][16];
#pragma unroll
    for (int c = 0; c < 4; c++)
#pragma unroll
      for (int d = 0; d < 16; d++) acc[c][d] = p.mb2[c * 16 + d];
#pragma unroll 4
    for (int k = 0; k < 64; k++) {
      const float hv = xs[k][t];
#pragma unroll
      for (int c = 0; c < 4; c++) fma16(hv, &mlpw[k * 64 + c * 16], acc[c]);
    }
#pragma unroll
    for (int c = 0; c < 4; c++)
#pragma unroll
      for (int d = 0; d < 16; d++)
        xs[c * 16 + d][t] = sigm(fmaf(p.mg2[c * 16 + d] * INVC, acc[c][d], p.mbe2[c * 16 + d]));
  }
  __syncthreads();
  // mlp3: restage mW3 over rows 96..175, then rows 0..63 -> rows 0..63
  {
    float4* d4 = (float4*)mlpw;
    const float4* s = (const float4*)p.mW3;
#pragma unroll 1
    for (int i = t; i < 1024; i += NT) d4[i] = s[i];
  }
  __syncthreads();
  {
    float acc[4][16];
#pragma unroll
    for (int c = 0; c < 4; c++)
#pragma unroll
      for (int d = 0; d < 16; d++) acc[c][d] = p.mb3[c * 16 + d];
#pragma unroll 4
    for (int k = 0; k < 64; k++) {
      const float hv = xs[k][t];
#pragma unroll
      for (int c = 0; c < 4; c++) fma16(hv, &mlpw[k * 64 + c * 16], acc[c]);
    }
#pragma unroll
    for (int c = 0; c < 4; c++)
#pragma unroll
      for (int d = 0; d < 16; d++)
        xs[c * 16 + d][t] = sigm(fmaf(p.mg3[c * 16 + d] * INVC, acc[c][d], p.mbe3[c * 16 + d]));
  }
  // mlp4: rows 0..63 -> out; weights broadcast from wl[1024..1087]
  {
    float a0 = p.mb4[0], a1 = 0.f, a2 = 0.f, a3 = 0.f;
#pragma unroll 4
    for (int k = 0; k < 16; k++) {
      a0 = fmaf(xs[k * 4 + 0][t], wl[1024 + k * 4 + 0], a0);
      a1 = fmaf(xs[k * 4 + 1][t], wl[1024 + k * 4 + 1], a1);
      a2 = fmaf(xs[k * 4 + 2][t], wl[1024 + k * 4 + 2], a2);
      a3 = fmaf(xs[k * 4 + 3][t], wl[1024 + k * 4 + 3], a3);
    }
    p.out[g] = (a0 + a1) + (a2 + a3);
  }
}

extern "C" void kernel_launch(void* const* d_in, const int* in_sizes, int n_in,
                              void* d_out, int out_size, void* d_ws, size_t ws_size,
                              hipStream_t stream) {
  P p;
  p.node_feat = (const float*)d_in[0];
  p.edge_feat = (const float*)d_in[1];
  p.ei        = (const int*)d_in[2];
  p.W_ne  = (const float*)d_in[3];  p.b_ne  = (const float*)d_in[4];
  p.g_ne  = (const float*)d_in[5];  p.be_ne = (const float*)d_in[6];
  p.W_ee  = (const float*)d_in[7];  p.b_ee  = (const float*)d_in[8];
  p.msg_W1 = (const float*)d_in[9];  p.msg_b1 = (const float*)d_in[10];
  p.msg_W2 = (const float*)d_in[11]; p.msg_b2 = (const float*)d_in[12];
  p.upd_W1 = (const float*)d_in[13]; p.upd_b1 = (const float*)d_in[14];
  p.upd_g1 = (const float*)d_in[15]; p.upd_be1 = (const float*)d_in[16];
  p.upd_W2 = (const float*)d_in[17]; p.upd_b2 = (const float*)d_in[18];
  p.upd_g2 = (const float*)d_in[19]; p.upd_be2 = (const float*)d_in[20];
  p.Wp  = (const float*)d_in[21]; p.bp  = (const float*)d_in[22];
  p.gp  = (const float*)d_in[23]; p.bep = (const float*)d_in[24];
  p.mW1 = (const float*)d_in[25]; p.mb1 = (const float*)d_in[26];
  p.mg1 = (const float*)d_in[27]; p.mbe1 = (const float*)d_in[28];
  p.mW2 = (const float*)d_in[29]; p.mb2 = (const float*)d_in[30];
  p.mg2 = (const float*)d_in[31]; p.mbe2 = (const float*)d_in[32];
  p.mW3 = (const float*)d_in[33]; p.mb3 = (const float*)d_in[34];
  p.mg3 = (const float*)d_in[35]; p.mbe3 = (const float*)d_in[36];
  p.mW4 = (const float*)d_in[37]; p.mb4 = (const float*)d_in[38];
  p.out = (float*)d_out;

  hipLaunchKernelGGL(gnn_kernel, dim3(NB / NT), dim3(NT), 0, stream, p);
}